// Round 11
// baseline (395.080 us; speedup 1.0000x reference)
//
#include <hip/hip_runtime.h>
#include <math.h>

constexpr int BB  = 32;
constexpr int SQL = 2048;
constexpr int SKL = 2048;
constexpr int DD  = 64;

using f32x4 = __attribute__((ext_vector_type(4))) float;
using bfrag = __attribute__((ext_vector_type(8))) short;   // 8 bf16 = 4 VGPR

static __device__ __forceinline__ unsigned short f2bf(float x) {
    unsigned u = __float_as_uint(x);
    u = u + 0x7FFFu + ((u >> 16) & 1u);          // round-nearest-even
    return (unsigned short)(u >> 16);
}
static __device__ __forceinline__ float bf2f(unsigned short h) {
    return __uint_as_float((unsigned)h << 16);
}

// async global->LDS, 16 B per lane (wave-uniform base + lane*16 dest;
// GLOBAL source address is per-lane -> source-side permutation is free)
static __device__ __forceinline__ void gld16(const void* g, void* l) {
    __builtin_amdgcn_global_load_lds(
        (const __attribute__((address_space(1))) void*)(size_t)g,
        (__attribute__((address_space(3))) void*)(unsigned)(size_t)l,
        16, 0, 0);
}

// ---- prepass: k fp32 -> swizzled bf16 hi/lo records (proven r6/r9/r10).
// Per (b,c): 256 B = [hi 128B][lo 128B]; 16-B groups XOR'd by ((c&7)<<4).
__global__ __launch_bounds__(256) void split_k_swz(
    const float* __restrict__ k, unsigned char* __restrict__ kswz)
{
    const int i0 = blockIdx.x * blockDim.x + threadIdx.x;  // (b,c,g)
    const int g  = i0 & 7;
    const int c  = (i0 >> 3) & 2047;
    const int b  = i0 >> 14;
    const float* kp = k + ((size_t)(b * 2048 + c)) * DD + g * 8;
    bfrag h, lo;
    #pragma unroll
    for (int j = 0; j < 8; ++j) {
        const float x = kp[j];
        const unsigned short hh = f2bf(x);
        h[j]  = (short)hh;
        lo[j] = (short)f2bf(x - bf2f(hh));
    }
    const int sw = (c & 7) << 4;
    unsigned char* rec = kswz + ((size_t)(b * 2048 + c)) * 256;
    *(bfrag*)(rec + ((g * 16) ^ sw))       = h;
    *(bfrag*)(rec + 128 + ((g * 16) ^ sw)) = lo;
}

// ---- main: block = 1024 thr = 16 waves = 16 q-rows x 2048 cols.
// Wave w owns cols [w*128,(w+1)*128): 8 tiles of 16 cols. Per wave LDS =
// 5 KB (k 4 KB single buffer + mask 1 KB), 80 KB/block -> 2 blocks/CU ->
// 32 waves/CU. VGPR forced <=64 -> 8 waves/SIMD; latency hidden by TLP.
template<bool PRE>
__global__ __launch_bounds__(1024, 8) void sdpa_v11(
    const float* __restrict__ q, const float* __restrict__ k,
    const int* __restrict__ mask, const unsigned char* __restrict__ kswz,
    float* __restrict__ out)
{
    __shared__ char pool[81920];           // 16 waves x [k 4K | mask 1K]

    const int t   = threadIdx.x;
    const int l   = t & 63;
    const int w   = t >> 6;
    const int lr  = l & 15;
    const int lg  = l >> 4;
    const int bid = blockIdx.x;
    const int swz = (bid & 7) * 512 + (bid >> 3);   // bijective XCD chunking
    const int b   = swz >> 7;                       // batch
    const int r0  = (swz & 127) * 16;               // q-row base
    const int c0  = w * 128;                        // wave's col base
    const size_t rowg = (size_t)b * SQL + (size_t)(r0 + lr);  // lane's q-row
    const int swk = (lr & 7) << 4;                  // k LDS swizzle key

    char* kseg = pool + w * 5120;
    char* mseg = kseg + 4096;

    const char* ksrc = PRE ? (const char*)(kswz + ((size_t)b * SKL + c0) * 256) : nullptr;
    const float* kraw = PRE ? nullptr : k + (size_t)b * SKL * DD;
    // mask DMA: lane l fetches int4 (row=l>>2, colgroup=(l&3)^((l>>3)&3))
    const int* msrc = mask + ((size_t)b * SQL + (size_t)(r0 + (l >> 2))) * SKL
                           + c0 + (((l & 3) ^ ((l >> 3) & 3)) << 2);
    const int moff = lr * 64 + ((lg ^ ((lr >> 1) & 3)) << 4);

#define STAGE(T)                                                               \
    do {                                                                       \
        if constexpr (PRE) {                                                   \
            const char* _ks = ksrc + (size_t)(T) * 4096;                       \
            gld16(_ks + l * 16,        kseg + l * 16);                         \
            gld16(_ks + 1024 + l * 16, kseg + 1024 + l * 16);                  \
            gld16(_ks + 2048 + l * 16, kseg + 2048 + l * 16);                  \
            gld16(_ks + 3072 + l * 16, kseg + 3072 + l * 16);                  \
            gld16(msrc + (T) * 16, mseg + l * 16);                             \
        } else {                                                               \
            const float* _kc = kraw + (size_t)(c0 + (T) * 16 + lr) * DD;       \
            const f32x4 _a0 = *(const f32x4*)(_kc + lg * 8);                   \
            const f32x4 _a1 = *(const f32x4*)(_kc + lg * 8 + 4);               \
            const f32x4 _b0 = *(const f32x4*)(_kc + (lg + 4) * 8);             \
            const f32x4 _b1 = *(const f32x4*)(_kc + (lg + 4) * 8 + 4);         \
            bfrag _h, _o;                                                      \
            _Pragma("unroll")                                                  \
            for (int _j = 0; _j < 4; ++_j) {                                   \
                unsigned short _t2;                                            \
                _t2 = f2bf(_a0[_j]); _h[_j]   = (short)_t2;                    \
                _o[_j]   = (short)f2bf(_a0[_j] - bf2f(_t2));                   \
                _t2 = f2bf(_a1[_j]); _h[_j+4] = (short)_t2;                    \
                _o[_j+4] = (short)f2bf(_a1[_j] - bf2f(_t2));                   \
            }                                                                  \
            char* _rec = kseg + lr * 256;                                      \
            *(bfrag*)(_rec + ((lg * 16) ^ swk))       = _h;                    \
            *(bfrag*)(_rec + 128 + ((lg * 16) ^ swk)) = _o;                    \
            _Pragma("unroll")                                                  \
            for (int _j = 0; _j < 4; ++_j) {                                   \
                unsigned short _t2;                                            \
                _t2 = f2bf(_b0[_j]); _h[_j]   = (short)_t2;                    \
                _o[_j]   = (short)f2bf(_b0[_j] - bf2f(_t2));                   \
                _t2 = f2bf(_b1[_j]); _h[_j+4] = (short)_t2;                    \
                _o[_j+4] = (short)f2bf(_b1[_j] - bf2f(_t2));                   \
            }                                                                  \
            *(bfrag*)(_rec + (((lg + 4) * 16) ^ swk))       = _h;              \
            *(bfrag*)(_rec + 128 + (((lg + 4) * 16) ^ swk)) = _o;              \
            const int4 _mv = *(const int4*)(msrc + (T) * 16);                  \
            *(int4*)(mseg + l * 16) = _mv;                                     \
        }                                                                      \
    } while (0)

#define ITER(T)                                                                \
    do {                                                                       \
        if constexpr (PRE)                                                     \
            asm volatile("s_waitcnt vmcnt(0)" ::: "memory");                   \
        const char* _c = kseg + lr * 256;                                      \
        const bfrag _kh0 = *(const bfrag*)(_c + ((lg * 16) ^ swk));            \
        const bfrag _kh1 = *(const bfrag*)(_c + (((lg + 4) * 16) ^ swk));      \
        const bfrag _kl0 = *(const bfrag*)(_c + 128 + ((lg * 16) ^ swk));      \
        const bfrag _kl1 = *(const bfrag*)(_c + 128 + (((lg + 4) * 16) ^ swk));\
        const int4 _mv = *(const int4*)(mseg + moff);                          \
        asm volatile("s_waitcnt lgkmcnt(0)" ::: "memory");                     \
        __builtin_amdgcn_sched_barrier(0);                                     \
        if constexpr ((T) + 1 < 8) STAGE((T) + 1);                             \
        f32x4 _a = {0.f, 0.f, 0.f, 0.f};                                       \
        _a = __builtin_amdgcn_mfma_f32_16x16x32_bf16(_kl0, qh0, _a, 0, 0, 0);  \
        _a = __builtin_amdgcn_mfma_f32_16x16x32_bf16(_kh0, ql0, _a, 0, 0, 0);  \
        _a = __builtin_amdgcn_mfma_f32_16x16x32_bf16(_kh0, qh0, _a, 0, 0, 0);  \
        _a = __builtin_amdgcn_mfma_f32_16x16x32_bf16(_kl1, qh1, _a, 0, 0, 0);  \
        _a = __builtin_amdgcn_mfma_f32_16x16x32_bf16(_kh1, ql1, _a, 0, 0, 0);  \
        _a = __builtin_amdgcn_mfma_f32_16x16x32_bf16(_kh1, qh1, _a, 0, 0, 0);  \
        const float _e0 = (_mv.x != 0) ? exp2f(_a[0]) : 0.f;                   \
        const float _e1 = (_mv.y != 0) ? exp2f(_a[1]) : 0.f;                   \
        const float _e2 = (_mv.z != 0) ? exp2f(_a[2]) : 0.f;                   \
        const float _e3 = (_mv.w != 0) ? exp2f(_a[3]) : 0.f;                   \
        psum += (_e0 + _e1) + (_e2 + _e3);                                     \
        asm volatile("v_cvt_pk_bf16_f32 %0, %1, %2"                            \
                     : "=v"(sc[2 * (T)]) : "v"(_e0), "v"(_e1));                \
        asm volatile("v_cvt_pk_bf16_f32 %0, %1, %2"                            \
                     : "=v"(sc[2 * (T) + 1]) : "v"(_e2), "v"(_e3));            \
    } while (0)

    // ---- prologue: start tile-0 DMA before anything else
    STAGE(0);

    // ---- q fragments (B operand), scale (log2e/8) folded, hi/lo split
    constexpr float QS = 0.18033688011112042f;      // 0.125 * log2(e)
    bfrag qh0, ql0, qh1, ql1;
    {
        const float* qp = q + rowg * DD + lg * 8;
        const f32x4 x0 = *reinterpret_cast<const f32x4*>(qp);
        const f32x4 x1 = *reinterpret_cast<const f32x4*>(qp + 4);
        const f32x4 y0 = *reinterpret_cast<const f32x4*>(qp + 32);
        const f32x4 y1 = *reinterpret_cast<const f32x4*>(qp + 36);
        #pragma unroll
        for (int j = 0; j < 4; ++j) {
            float a = x0[j] * QS, c = x1[j] * QS;
            float d = y0[j] * QS, e = y1[j] * QS;
            unsigned short h;
            h = f2bf(a); qh0[j]     = (short)h; ql0[j]     = (short)f2bf(a - bf2f(h));
            h = f2bf(c); qh0[j + 4] = (short)h; ql0[j + 4] = (short)f2bf(c - bf2f(h));
            h = f2bf(d); qh1[j]     = (short)h; ql1[j]     = (short)f2bf(d - bf2f(h));
            h = f2bf(e); qh1[j + 4] = (short)h; ql1[j + 4] = (short)f2bf(e - bf2f(h));
        }
    }

    unsigned sc[16];                  // packed bf16 exp values (16 VGPR)
    float psum = 0.f;

    ITER(0); ITER(1); ITER(2); ITER(3);
    ITER(4); ITER(5); ITER(6); ITER(7);
#undef ITER
#undef STAGE

    // ---- row sums: lanes {l, l^16, l^32, l^48} share a q-row
    float s = psum;
    s += __shfl_xor(s, 16, 64);
    s += __shfl_xor(s, 32, 64);

    __syncthreads();                  // all LDS traffic done; pool reusable
    float* s_red = (float*)pool;      // aliased scratch (16x16 floats)
    if (l < 16) s_red[w * 16 + lr] = s;
    __syncthreads();

    float tot = 0.f;
    #pragma unroll
    for (int ww = 0; ww < 16; ++ww)
        tot += s_red[ww * 16 + lr];
    const float rinv = 1.0f / tot;

    // ---- unpack, normalize, float4 store
    float* op = out + rowg * SKL + c0 + lg * 4;
    #pragma unroll
    for (int T = 0; T < 8; ++T) {
        const unsigned p01 = sc[2 * T];
        const unsigned p23 = sc[2 * T + 1];
        f32x4 o;
        o[0] = bf2f((unsigned short)(p01 & 0xffffu)) * rinv;
        o[1] = bf2f((unsigned short)(p01 >> 16))     * rinv;
        o[2] = bf2f((unsigned short)(p23 & 0xffffu)) * rinv;
        o[3] = bf2f((unsigned short)(p23 >> 16))     * rinv;
        *reinterpret_cast<f32x4*>(op + T * 16) = o;
    }
}

extern "C" void kernel_launch(void* const* d_in, const int* in_sizes, int n_in,
                              void* d_out, int out_size, void* d_ws, size_t ws_size,
                              hipStream_t stream) {
    const float* q    = (const float*)d_in[0];
    const float* k    = (const float*)d_in[1];
    const int*   mask = (const int*)d_in[2];
    float*       out  = (float*)d_out;

    const size_t KS_B = (size_t)BB * SKL * 256;   // 16.78 MB swizzled k

    dim3 grid(4096);    // XCD-swizzled in-kernel; 16 waves each

    if (ws_size >= KS_B) {
        unsigned char* ksp = (unsigned char*)d_ws;
        split_k_swz<<<2048, 256, 0, stream>>>(k, ksp);
        sdpa_v11<true><<<grid, 1024, 0, stream>>>(q, k, mask, ksp, out);
    } else {
        sdpa_v11<false><<<grid, 1024, 0, stream>>>(q, k, mask, nullptr, out);
    }
}

// Round 13
// 335.698 us; speedup vs baseline: 1.1769x; 1.1769x over previous
//
#include <hip/hip_runtime.h>
#include <math.h>

constexpr int BB  = 32;
constexpr int SQL = 2048;
constexpr int SKL = 2048;
constexpr int DD  = 64;

using f32x4 = __attribute__((ext_vector_type(4))) float;
using bfrag = __attribute__((ext_vector_type(8))) short;   // 8 bf16 = 4 VGPR
typedef unsigned long long u64;

static __device__ __forceinline__ unsigned short f2bf(float x) {
    unsigned u = __float_as_uint(x);
    u = u + 0x7FFFu + ((u >> 16) & 1u);          // round-nearest-even
    return (unsigned short)(u >> 16);
}
static __device__ __forceinline__ float bf2f(unsigned short h) {
    return __uint_as_float((unsigned)h << 16);
}

// async global->LDS, 16 B per lane (wave-uniform base + lane*16 dest)
static __device__ __forceinline__ void gld16(const void* g, void* l) {
    __builtin_amdgcn_global_load_lds(
        (const __attribute__((address_space(1))) void*)(size_t)g,
        (__attribute__((address_space(3))) void*)(unsigned)(size_t)l,
        16, 0, 0);
}

// ---- prepass 1: mask int32 -> 1 bit/elem, natural col order (proven r8/r9)
__global__ __launch_bounds__(256) void compress_mask(
    const int* __restrict__ m, unsigned char* __restrict__ bm)
{
    const int t = threadIdx.x;
    const size_t g0 = (size_t)blockIdx.x * 1024 + t;
    const int4* mp = (const int4*)m;
    int4 a0 = mp[(g0)       * 2], a1 = mp[(g0)       * 2 + 1];
    int4 b0 = mp[(g0 + 256) * 2], b1 = mp[(g0 + 256) * 2 + 1];
    int4 c0 = mp[(g0 + 512) * 2], c1 = mp[(g0 + 512) * 2 + 1];
    int4 d0 = mp[(g0 + 768) * 2], d1 = mp[(g0 + 768) * 2 + 1];
#define PACK8(v0, v1)                                                         \
    (unsigned char)((v0.x != 0 ? 1u : 0u)  | (v0.y != 0 ? 2u : 0u)   |        \
                    (v0.z != 0 ? 4u : 0u)  | (v0.w != 0 ? 8u : 0u)   |        \
                    (v1.x != 0 ? 16u : 0u) | (v1.y != 0 ? 32u : 0u)  |        \
                    (v1.z != 0 ? 64u : 0u) | (v1.w != 0 ? 128u : 0u))
    bm[g0]       = PACK8(a0, a1);
    bm[g0 + 256] = PACK8(b0, b1);
    bm[g0 + 512] = PACK8(c0, c1);
    bm[g0 + 768] = PACK8(d0, d1);
#undef PACK8
}

// ---- prepass 2: k fp32 -> swizzled bf16 hi/lo records (proven r6/r9).
// Per (b,c): 256 B = [hi 128B][lo 128B]; 16-B groups XOR'd by ((c&7)<<4).
__global__ __launch_bounds__(256) void split_k_swz(
    const float* __restrict__ k, unsigned char* __restrict__ kswz)
{
    const int i0 = blockIdx.x * blockDim.x + threadIdx.x;  // (b,c,g)
    const int g  = i0 & 7;
    const int c  = (i0 >> 3) & 2047;
    const int b  = i0 >> 14;
    const float* kp = k + ((size_t)(b * 2048 + c)) * DD + g * 8;
    bfrag h, lo;
    #pragma unroll
    for (int j = 0; j < 8; ++j) {
        const float x = kp[j];
        const unsigned short hh = f2bf(x);
        h[j]  = (short)hh;
        lo[j] = (short)f2bf(x - bf2f(hh));
    }
    const int sw = (c & 7) << 4;
    unsigned char* rec = kswz + ((size_t)(b * 2048 + c)) * 256;
    *(bfrag*)(rec + ((g * 16) ^ sw))       = h;
    *(bfrag*)(rec + 128 + ((g * 16) ^ sw)) = lo;
}

// ---- main: block = 8 waves = 32 q-rows x 2048 cols; wave w owns 256 cols.
// Each wave computes TWO 16-row groups per k-tile, sharing k fragments ->
// k L2 traffic halves vs 16-row blocks. k fed by gld16 DMA into a DEPTH-3
// ring of wave-private LDS buffers; counted vmcnt ledger: S(T) is complete
// once we drain to 8 (= the two newer stages in flight). Tail: 4, then 0.
template<bool PRE>
__global__ __launch_bounds__(512, 2) void sdpa_v13(
    const float* __restrict__ q, const float* __restrict__ k,
    const int* __restrict__ mask, const unsigned char* __restrict__ bm,
    const unsigned char* __restrict__ kswz, float* __restrict__ out)
{
    __shared__ char pool[8 * 12288 + 1024];   // 8 waves x 3 k-bufs + s_red

    const int t   = threadIdx.x;
    const int l   = t & 63;
    const int w   = t >> 6;
    const int lr  = l & 15;
    const int lg  = l >> 4;
    const int bid = blockIdx.x;
    const int swz = (bid & 7) * 256 + (bid >> 3);   // bijective XCD chunking
    const int b   = swz >> 6;                       // batch
    const int r0  = (swz & 63) * 32;                // q-row base (32 rows)
    const int c0  = w * 256;                        // wave's col base
    const size_t row0 = (size_t)b * SQL + (size_t)(r0 + lr);        // g0 row
    const size_t row1 = row0 + 16;                                  // g1 row
    const int swk = (lr & 7) << 4;                  // k LDS swizzle key

    char* kseg = pool + w * 12288;
    const char*  ksrc = PRE ? (const char*)(kswz + ((size_t)b * SKL + c0) * 256) : nullptr;
    const float* kraw = PRE ? nullptr : k + (size_t)b * SKL * DD;
    const int*   mr0  = PRE ? nullptr : mask + row0 * SKL + c0 + lg * 4;
    const int*   mr1  = PRE ? nullptr : mask + row1 * SKL + c0 + lg * 4;

#define STAGE(T)                                                               \
    do {                                                                       \
        char* _kd = kseg + ((T) % 3) * 4096;                                   \
        if constexpr (PRE) {                                                   \
            const char* _ks = ksrc + (size_t)(T) * 4096;                       \
            gld16(_ks + l * 16,        _kd + l * 16);                          \
            gld16(_ks + 1024 + l * 16, _kd + 1024 + l * 16);                   \
            gld16(_ks + 2048 + l * 16, _kd + 2048 + l * 16);                   \
            gld16(_ks + 3072 + l * 16, _kd + 3072 + l * 16);                   \
        } else {                                                               \
            const float* _kc = kraw + (size_t)(c0 + (T) * 16 + lr) * DD;       \
            const f32x4 _a0 = *(const f32x4*)(_kc + lg * 8);                   \
            const f32x4 _a1 = *(const f32x4*)(_kc + lg * 8 + 4);               \
            const f32x4 _b0 = *(const f32x4*)(_kc + (lg + 4) * 8);             \
            const f32x4 _b1 = *(const f32x4*)(_kc + (lg + 4) * 8 + 4);         \
            bfrag _h, _o;                                                      \
            _Pragma("unroll")                                                  \
            for (int _j = 0; _j < 4; ++_j) {                                   \
                unsigned short _t2;                                            \
                _t2 = f2bf(_a0[_j]); _h[_j]   = (short)_t2;                    \
                _o[_j]   = (short)f2bf(_a0[_j] - bf2f(_t2));                   \
                _t2 = f2bf(_a1[_j]); _h[_j+4] = (short)_t2;                    \
                _o[_j+4] = (short)f2bf(_a1[_j] - bf2f(_t2));                   \
            }                                                                  \
            char* _rec = _kd + lr * 256;                                       \
            *(bfrag*)(_rec + ((lg * 16) ^ swk))       = _h;                    \
            *(bfrag*)(_rec + 128 + ((lg * 16) ^ swk)) = _o;                    \
            _Pragma("unroll")                                                  \
            for (int _j = 0; _j < 4; ++_j) {                                   \
                unsigned short _t2;                                            \
                _t2 = f2bf(_b0[_j]); _h[_j]   = (short)_t2;                    \
                _o[_j]   = (short)f2bf(_b0[_j] - bf2f(_t2));                   \
                _t2 = f2bf(_b1[_j]); _h[_j+4] = (short)_t2;                    \
                _o[_j+4] = (short)f2bf(_b1[_j] - bf2f(_t2));                   \
            }                                                                  \
            *(bfrag*)(_rec + (((lg + 4) * 16) ^ swk))       = _h;              \
            *(bfrag*)(_rec + 128 + (((lg + 4) * 16) ^ swk)) = _o;              \
        }                                                                      \
    } while (0)

    // ---- prologue: start tile-0 DMA first
    STAGE(0);

    // ---- q fragments for both row groups, scale (log2e/8) folded, hi/lo
    constexpr float QS = 0.18033688011112042f;      // 0.125 * log2(e)
    bfrag qh0a, ql0a, qh1a, ql1a;                   // group 0 (rows r0..+15)
    bfrag qh0b, ql0b, qh1b, ql1b;                   // group 1 (rows +16..31)
#define LOADQ(ROW, H0, L0, H1, L1)                                             \
    do {                                                                       \
        const float* _qp = q + (ROW) * DD + lg * 8;                            \
        const f32x4 _x0 = *(const f32x4*)_qp;                                  \
        const f32x4 _x1 = *(const f32x4*)(_qp + 4);                            \
        const f32x4 _y0 = *(const f32x4*)(_qp + 32);                           \
        const f32x4 _y1 = *(const f32x4*)(_qp + 36);                           \
        _Pragma("unroll")                                                      \
        for (int _j = 0; _j < 4; ++_j) {                                       \
            float _a = _x0[_j] * QS, _c = _x1[_j] * QS;                        \
            float _d = _y0[_j] * QS, _e = _y1[_j] * QS;                        \
            unsigned short _h;                                                 \
            _h = f2bf(_a); H0[_j]   = (short)_h; L0[_j]   = (short)f2bf(_a - bf2f(_h)); \
            _h = f2bf(_c); H0[_j+4] = (short)_h; L0[_j+4] = (short)f2bf(_c - bf2f(_h)); \
            _h = f2bf(_d); H1[_j]   = (short)_h; L1[_j]   = (short)f2bf(_d - bf2f(_h)); \
            _h = f2bf(_e); H1[_j+4] = (short)_h; L1[_j+4] = (short)f2bf(_e - bf2f(_h)); \
        }                                                                      \
    } while (0)
    LOADQ(row0, qh0a, ql0a, qh1a, ql1a);
    LOADQ(row1, qh0b, ql0b, qh1b, ql1b);
#undef LOADQ

    // ---- bitmask: ALL 256 wave cols for both rows, loaded up front
    u64 ma0 = 0, ma1 = 0, ma2 = 0, ma3 = 0;
    u64 mb0 = 0, mb1 = 0, mb2 = 0, mb3 = 0;
    if constexpr (PRE) {
        const ulonglong2* wpa = (const ulonglong2*)(bm + row0 * (SKL / 8) + w * 32);
        const ulonglong2* wpb = (const ulonglong2*)(bm + row1 * (SKL / 8) + w * 32);
        const ulonglong2 va0 = wpa[0], va1 = wpa[1];
        const ulonglong2 vb0 = wpb[0], vb1 = wpb[1];
        ma0 = va0.x; ma1 = va0.y; ma2 = va1.x; ma3 = va1.y;
        mb0 = vb0.x; mb1 = vb0.y; mb2 = vb1.x; mb3 = vb1.y;
    }

    STAGE(1);
    STAGE(2);

    unsigned sc[64];                  // packed bf16 exp: [tile][g][pair]
    float psum0 = 0.f, psum1 = 0.f;

#define ITER(T, VMC, MA, MB)                                                   \
    do {                                                                       \
        if constexpr (PRE)                                                     \
            asm volatile("s_waitcnt vmcnt(" #VMC ")" ::: "memory");            \
        const char* _c = kseg + ((T) % 3) * 4096 + lr * 256;                   \
        const bfrag _kh0 = *(const bfrag*)(_c + ((lg * 16) ^ swk));            \
        const bfrag _kh1 = *(const bfrag*)(_c + (((lg + 4) * 16) ^ swk));      \
        const bfrag _kl0 = *(const bfrag*)(_c + 128 + ((lg * 16) ^ swk));      \
        const bfrag _kl1 = *(const bfrag*)(_c + 128 + (((lg + 4) * 16) ^ swk));\
        int4 _mva, _mvb;                                                       \
        if constexpr (!PRE) {                                                  \
            _mva = *(const int4*)(mr0 + (T) * 16);                             \
            _mvb = *(const int4*)(mr1 + (T) * 16);                             \
        }                                                                      \
        asm volatile("s_waitcnt lgkmcnt(0)" ::: "memory");                     \
        __builtin_amdgcn_sched_barrier(0);                                     \
        if constexpr ((T) + 3 < 16) STAGE((T) + 3);                            \
        /* group 0: hh chain + mixed chain */                                  \
        f32x4 _h = {0.f, 0.f, 0.f, 0.f};                                       \
        f32x4 _m = {0.f, 0.f, 0.f, 0.f};                                       \
        _h = __builtin_amdgcn_mfma_f32_16x16x32_bf16(_kh0, qh0a, _h, 0, 0, 0); \
        _m = __builtin_amdgcn_mfma_f32_16x16x32_bf16(_kh0, ql0a, _m, 0, 0, 0); \
        _h = __builtin_amdgcn_mfma_f32_16x16x32_bf16(_kh1, qh1a, _h, 0, 0, 0); \
        _m = __builtin_amdgcn_mfma_f32_16x16x32_bf16(_kl0, qh0a, _m, 0, 0, 0); \
        _m = __builtin_amdgcn_mfma_f32_16x16x32_bf16(_kh1, ql1a, _m, 0, 0, 0); \
        _m = __builtin_amdgcn_mfma_f32_16x16x32_bf16(_kl1, qh1a, _m, 0, 0, 0); \
        const f32x4 _s0 = _h + _m;                                             \
        /* group 1 */                                                          \
        f32x4 _h2 = {0.f, 0.f, 0.f, 0.f};                                      \
        f32x4 _m2 = {0.f, 0.f, 0.f, 0.f};                                      \
        _h2 = __builtin_amdgcn_mfma_f32_16x16x32_bf16(_kh0, qh0b, _h2, 0, 0, 0);\
        _m2 = __builtin_amdgcn_mfma_f32_16x16x32_bf16(_kh0, ql0b, _m2, 0, 0, 0);\
        _h2 = __builtin_amdgcn_mfma_f32_16x16x32_bf16(_kh1, qh1b, _h2, 0, 0, 0);\
        _m2 = __builtin_amdgcn_mfma_f32_16x16x32_bf16(_kl0, qh0b, _m2, 0, 0, 0);\
        _m2 = __builtin_amdgcn_mfma_f32_16x16x32_bf16(_kh1, ql1b, _m2, 0, 0, 0);\
        _m2 = __builtin_amdgcn_mfma_f32_16x16x32_bf16(_kl1, qh1b, _m2, 0, 0, 0);\
        const f32x4 _s1 = _h2 + _m2;                                           \
        unsigned _n0, _n1;                                                     \
        if constexpr (PRE) {                                                   \
            _n0 = (unsigned)((MA) >> (((T) & 3) * 16 + lg * 4)) & 0xFu;        \
            _n1 = (unsigned)((MB) >> (((T) & 3) * 16 + lg * 4)) & 0xFu;        \
        } else {                                                               \
            _n0 = (_mva.x != 0 ? 1u : 0u) | (_mva.y != 0 ? 2u : 0u)            \
                | (_mva.z != 0 ? 4u : 0u) | (_mva.w != 0 ? 8u : 0u);           \
            _n1 = (_mvb.x != 0 ? 1u : 0u) | (_mvb.y != 0 ? 2u : 0u)            \
                | (_mvb.z != 0 ? 4u : 0u) | (_mvb.w != 0 ? 8u : 0u);           \
        }                                                                      \
        const float _e0 = (_n0 & 1u) ? exp2f(_s0[0]) : 0.f;                    \
        const float _e1 = (_n0 & 2u) ? exp2f(_s0[1]) : 0.f;                    \
        const float _e2 = (_n0 & 4u) ? exp2f(_s0[2]) : 0.f;                    \
        const float _e3 = (_n0 & 8u) ? exp2f(_s0[3]) : 0.f;                    \
        const float _f0 = (_n1 & 1u) ? exp2f(_s1[0]) : 0.f;                    \
        const float _f1 = (_n1 & 2u) ? exp2f(_s1[1]) : 0.f;                    \
        const float _f2 = (_n1 & 4u) ? exp2f(_s1[2]) : 0.f;                    \
        const float _f3 = (_n1 & 8u) ? exp2f(_s1[3]) : 0.f;                    \
        psum0 += (_e0 + _e1) + (_e2 + _e3);                                    \
        psum1 += (_f0 + _f1) + (_f2 + _f3);                                    \
        asm volatile("v_cvt_pk_bf16_f32 %0, %1, %2"                            \
                     : "=v"(sc[4 * (T)])     : "v"(_e0), "v"(_e1));            \
        asm volatile("v_cvt_pk_bf16_f32 %0, %1, %2"                            \
                     : "=v"(sc[4 * (T) + 1]) : "v"(_e2), "v"(_e3));            \
        asm volatile("v_cvt_pk_bf16_f32 %0, %1, %2"                            \
                     : "=v"(sc[4 * (T) + 2]) : "v"(_f0), "v"(_f1));            \
        asm volatile("v_cvt_pk_bf16_f32 %0, %1, %2"                            \
                     : "=v"(sc[4 * (T) + 3]) : "v"(_f2), "v"(_f3));            \
    } while (0)

    // counted-vmcnt ledger (FIFO): S(T) complete once drained past the two
    // newer in-flight stages (8 loads). Tail drains 4 then 0.
    ITER(0,  8, ma0, mb0); ITER(1,  8, ma0, mb0);
    ITER(2,  8, ma0, mb0); ITER(3,  8, ma0, mb0);
    ITER(4,  8, ma1, mb1); ITER(5,  8, ma1, mb1);
    ITER(6,  8, ma1, mb1); ITER(7,  8, ma1, mb1);
    ITER(8,  8, ma2, mb2); ITER(9,  8, ma2, mb2);
    ITER(10, 8, ma2, mb2); ITER(11, 8, ma2, mb2);
    ITER(12, 8, ma3, mb3); ITER(13, 8, ma3, mb3);
    ITER(14, 4, ma3, mb3); ITER(15, 0, ma3, mb3);
#undef ITER
#undef STAGE

    // ---- row sums: lanes {l, l^16, l^32, l^48} share each q-row
    psum0 += __shfl_xor(psum0, 16, 64);
    psum0 += __shfl_xor(psum0, 32, 64);
    psum1 += __shfl_xor(psum1, 16, 64);
    psum1 += __shfl_xor(psum1, 32, 64);

    float* s_red = (float*)(pool + 8 * 12288);   // [wave][group][16]
    __syncthreads();
    if (l < 16) {
        s_red[w * 32 + lr]      = psum0;
        s_red[w * 32 + 16 + lr] = psum1;
    }
    __syncthreads();

    float tot0 = 0.f, tot1 = 0.f;
    #pragma unroll
    for (int ww = 0; ww < 8; ++ww) {
        tot0 += s_red[ww * 32 + lr];
        tot1 += s_red[ww * 32 + 16 + lr];
    }
    const float rinv0 = 1.0f / tot0;
    const float rinv1 = 1.0f / tot1;

    // ---- unpack, normalize, float4 stores (both row groups)
    float* op0 = out + row0 * SKL + c0 + lg * 4;
    float* op1 = out + row1 * SKL + c0 + lg * 4;
    #pragma unroll
    for (int T = 0; T < 16; ++T) {
        const unsigned pa = sc[4 * T], pb = sc[4 * T + 1];
        const unsigned pc = sc[4 * T + 2], pd = sc[4 * T + 3];
        f32x4 o0, o1;
        o0[0] = bf2f((unsigned short)(pa & 0xffffu)) * rinv0;
        o0[1] = bf2f((unsigned short)(pa >> 16))     * rinv0;
        o0[2] = bf2f((unsigned short)(pb & 0xffffu)) * rinv0;
        o0[3] = bf2f((unsigned short)(pb >> 16))     * rinv0;
        o1[0] = bf2f((unsigned short)(pc & 0xffffu)) * rinv1;
        o1[1] = bf2f((unsigned short)(pc >> 16))     * rinv1;
        o1[2] = bf2f((unsigned short)(pd & 0xffffu)) * rinv1;
        o1[3] = bf2f((unsigned short)(pd >> 16))     * rinv1;
        *reinterpret_cast<f32x4*>(op0 + T * 16) = o0;
        *reinterpret_cast<f32x4*>(op1 + T * 16) = o1;
    }
}

extern "C" void kernel_launch(void* const* d_in, const int* in_sizes, int n_in,
                              void* d_out, int out_size, void* d_ws, size_t ws_size,
                              hipStream_t stream) {
    const float* q    = (const float*)d_in[0];
    const float* k    = (const float*)d_in[1];
    const int*   mask = (const int*)d_in[2];
    float*       out  = (float*)d_out;

    const size_t BM_B = (size_t)BB * SQL * SKL / 8;   // 16.78 MB bitmask
    const size_t KS_B = (size_t)BB * SKL * 256;       // 16.78 MB swizzled k

    dim3 grid(2048);    // 32 batches x 64 row-blocks, XCD-swizzled in-kernel

    if (ws_size >= BM_B + KS_B) {
        unsigned char* bmp = (unsigned char*)d_ws;
        unsigned char* ksp = (unsigned char*)d_ws + BM_B;
        compress_mask<<<16384, 256, 0, stream>>>(mask, bmp);
        split_k_swz<<<2048, 256, 0, stream>>>(k, ksp);
        sdpa_v13<true><<<grid, 512, 0, stream>>>(q, k, mask, bmp, ksp, out);
    } else {
        sdpa_v13<false><<<grid, 512, 0, stream>>>(q, k, mask, nullptr, nullptr, out);
    }
}